// Round 12
// baseline (24.322 us; speedup 1.0000x reference)
//
#include <hip/hip_runtime.h>
#include <math.h>

namespace {

constexpr int NG     = 2048;
constexpr int IMG_H  = 160;
constexpr int IMG_W  = 224;
constexpr int HW     = IMG_H * IMG_W;   // 35840
constexpr int TS     = 8;               // tile size (8x8 px)
constexpr int TX     = IMG_W / TS;      // 28
constexpr int TYN    = IMG_H / TS;      // 20
constexpr int NTILE  = TX * TYN;        // 560

constexpr int NW     = 8;               // waves per block
constexpr int CAP    = 512;             // per-tile member list capacity

constexpr float TFX   = 0.5774f;
constexpr float TFY   = (float)(0.5774 * 160.0 / 224.0);
constexpr float ITFX  = (float)(1.0 / 0.5774);
constexpr float ITFY  = (float)(1.0 / (0.5774 * 160.0 / 224.0));
constexpr float FXC   = (float)(224.0 / (2.0 * 0.5774));
constexpr float FYC   = (float)(160.0 / (2.0 * (0.5774 * 160.0 / 224.0)));
constexpr float LIMX  = (float)(1.3 * 0.5774);
constexpr float LIMY  = (float)(1.3 * (0.5774 * 160.0 / 224.0));
constexpr float A_MIN = (float)(1.0 / 255.0);
constexpr float NEARP = 0.2f;
constexpr float LOWPASS = 0.3f;
constexpr float L2E   = 1.4426950408889634f;   // log2(e)
constexpr float LN2   = 0.6931471805599453f;
constexpr float L2_255 = 7.994353436858858f;   // log2(255)

// output float offsets (flat, in return order)
constexpr int O_COLOR = 0;
constexpr int O_RADII = 3 * HW;           // 107520
constexpr int O_DEPTH = O_RADII + NG;     // 109568
constexpr int O_OPAC  = O_DEPTH + HW;     // 145408
constexpr int O_NT    = O_OPAC + HW;      // 181248

} // namespace

struct G {
    float px, py, dxm, dym;
    float h0, h1, h2, l2op;
    float cr, cg, cb, tz;
    float radf;
    bool  valid;
};

// Full per-gaussian chain (R10 phase-C math, with v_rcp/v_rsq fast recips:
// rel err ~1e-7 vs the 2% output threshold).
__device__ __forceinline__ G g_chain(int i,
        const float* __restrict__ m3, const float* __restrict__ opc,
        const float* __restrict__ co, const float* __restrict__ sc,
        const float* __restrict__ ro, const float* __restrict__ vm)
{
    G g;
    float R00 = vm[0], R01 = vm[1], R02 = vm[2],  T0 = vm[3];
    float R10 = vm[4], R11 = vm[5], R12 = vm[6],  T1 = vm[7];
    float R20 = vm[8], R21 = vm[9], R22 = vm[10], T2 = vm[11];

    float mx = m3[3*i], my = m3[3*i+1], mz = m3[3*i+2];
    float tx = R00*mx + R01*my + R02*mz + T0;
    float ty = R10*mx + R11*my + R12*mz + T1;
    float tz = R20*mx + R21*my + R22*mz + T2;

    float itz = __builtin_amdgcn_rcpf(tz);
    float xr  = tx * itz, yr = ty * itz;
    float txz = fminf(LIMX, fmaxf(-LIMX, xr)) * tz;
    float tyz = fminf(LIMY, fmaxf(-LIMY, yr)) * tz;

    float qw = ro[4*i], qx = ro[4*i+1], qy = ro[4*i+2], qz = ro[4*i+3];
    float qn = __builtin_amdgcn_rsqf(qw*qw + qx*qx + qy*qy + qz*qz);
    qw *= qn; qx *= qn; qy *= qn; qz *= qn;
    float r00 = 1.0f - 2.0f*(qy*qy + qz*qz), r01 = 2.0f*(qx*qy - qw*qz), r02 = 2.0f*(qx*qz + qw*qy);
    float r10 = 2.0f*(qx*qy + qw*qz), r11 = 1.0f - 2.0f*(qx*qx + qz*qz), r12 = 2.0f*(qy*qz - qw*qx);
    float r20 = 2.0f*(qx*qz - qw*qy), r21 = 2.0f*(qy*qz + qw*qx), r22 = 1.0f - 2.0f*(qx*qx + qy*qy);

    float s0 = sc[3*i];   s0 = s0 * s0;
    float s1 = sc[3*i+1]; s1 = s1 * s1;
    float s2 = sc[3*i+2]; s2 = s2 * s2;

    float S00 = r00*r00*s0 + r01*r01*s1 + r02*r02*s2;
    float S01 = r00*r10*s0 + r01*r11*s1 + r02*r12*s2;
    float S02 = r00*r20*s0 + r01*r21*s1 + r02*r22*s2;
    float S11 = r10*r10*s0 + r11*r11*s1 + r12*r12*s2;
    float S12 = r10*r20*s0 + r11*r21*s1 + r12*r22*s2;
    float S22 = r20*r20*s0 + r21*r21*s1 + r22*r22*s2;

    float j00 = FXC * itz;
    float j02 = -FXC * txz * itz * itz;
    float j11 = FYC * itz;
    float j12 = -FYC * tyz * itz * itz;

    float Tm00 = j00*R00 + j02*R20, Tm01 = j00*R01 + j02*R21, Tm02 = j00*R02 + j02*R22;
    float Tm10 = j11*R10 + j12*R20, Tm11 = j11*R11 + j12*R21, Tm12 = j11*R12 + j12*R22;

    float M00 = Tm00*S00 + Tm01*S01 + Tm02*S02;
    float M01 = Tm00*S01 + Tm01*S11 + Tm02*S12;
    float M02 = Tm00*S02 + Tm01*S12 + Tm02*S22;
    float M10 = Tm10*S00 + Tm11*S01 + Tm12*S02;
    float M11 = Tm10*S01 + Tm11*S11 + Tm12*S12;
    float M12 = Tm10*S02 + Tm11*S12 + Tm12*S22;

    float cov00 = M00*Tm00 + M01*Tm01 + M02*Tm02;
    float cov01 = M00*Tm10 + M01*Tm11 + M02*Tm12;
    float cov11 = M10*Tm10 + M11*Tm11 + M12*Tm12;

    float a = cov00 + LOWPASS;
    float b = cov01;
    float c = cov11 + LOWPASS;
    float det = a*c - b*b;
    float dinv = __builtin_amdgcn_rcpf(det);
    float con0 = c * dinv, con1 = -b * dinv, con2 = a * dinv;

    float mid  = 0.5f * (a + c);
    float lam1 = mid + sqrtf(fmaxf(0.1f, mid*mid - det));
    g.radf = ceilf(3.0f * sqrtf(lam1));

    g.px = ((xr * ITFX + 1.0f) * (float)IMG_W - 1.0f) * 0.5f;
    g.py = ((yr * ITFY + 1.0f) * (float)IMG_H - 1.0f) * 0.5f;

    g.valid = (tz > NEARP) && (det > 0.0f) && (g.radf > 0.0f);

    g.l2op = __log2f(opc[i]);
    float tlin = fmaxf(0.0f, (g.l2op + L2_255) * LN2);
    g.dxm = sqrtf(2.0f * tlin * a) * 1.001f + 0.1f;
    g.dym = sqrtf(2.0f * tlin * c) * 1.001f + 0.1f;

    g.h0 = -0.5f * con0 * L2E;
    g.h1 = -con1 * L2E;
    g.h2 = -0.5f * con2 * L2E;
    g.cr = co[3*i]; g.cg = co[3*i+1]; g.cb = co[3*i+2];
    g.tz = tz;
    return g;
}

// Single fused kernel: one block (8 waves) per tile.
//  1) each thread runs 4 full chains; tile members -> LDS list (slot via LDS
//     atomic; order irrelevant, see 2)
//  2) stable rank sort of members by (tz, original idx) — identical
//     comparator to the global stable argsort restricted to this tile
//  3) wave wv composites the wv-th sorted chunk; LDS partials; wave 0 folds
//     in depth order and writes color/depth/opacity
//  4) blocks 0..255: wave wv computes gaussian blk*8+wv's radii and
//     n_touched (PURE per-gaussian: ref counts masked alpha>0, no T) by
//     scanning its bbox pixels — direct stores, no atomics, no zero-init.
__global__ __launch_bounds__(512) void k_mega(const float* __restrict__ means3D,
                                              const float* __restrict__ opac,
                                              const float* __restrict__ cols,
                                              const float* __restrict__ scales,
                                              const float* __restrict__ rots,
                                              const float* __restrict__ vm,
                                              const float* __restrict__ bg,
                                              float* __restrict__ out)
{
    __shared__ float Mrec[CAP][12];    // 24 KB member records
    __shared__ float Mkey[CAP];        // 2 KB depth keys
    __shared__ int   Midx[CAP];        // 2 KB original indices
    __shared__ int   Msrt[CAP];        // 2 KB sorted -> slot
    __shared__ float Lpart[NW][5][64]; // 10 KB per-wave partials
    __shared__ int   mcnt;

    int tid  = threadIdx.x;
    int lane = tid & 63;
    int wv   = tid >> 6;
    int tile = blockIdx.x;
    int tx = tile % TX, ty = tile / TX;
    float xmin = (float)(tx * TS), xmax = xmin + (float)(TS - 1);
    float ymin = (float)(ty * TS), ymax = ymin + (float)(TS - 1);

    if (tid == 0) mcnt = 0;
    __syncthreads();

    // ---- 1) chains + membership ----
    #pragma unroll
    for (int j = 0; j < NG / 512; ++j) {
        int i = tid + j * 512;
        G g = g_chain(i, means3D, opac, cols, scales, rots, vm);
        bool member = g.valid
                   && (g.px - g.dxm <= xmax) && (g.px + g.dxm >= xmin)
                   && (g.py - g.dym <= ymax) && (g.py + g.dym >= ymin);
        if (member) {
            int slot = atomicAdd(&mcnt, 1);
            if (slot < CAP) {
                Mrec[slot][0] = g.px;  Mrec[slot][1] = g.py;
                Mrec[slot][2] = g.h0;  Mrec[slot][3] = g.h1;
                Mrec[slot][4] = g.h2;  Mrec[slot][5] = g.l2op;
                Mrec[slot][6] = g.cr;  Mrec[slot][7] = g.cg;
                Mrec[slot][8] = g.cb;  Mrec[slot][9] = g.tz;
                Mkey[slot] = g.tz;
                Midx[slot] = i;
            }
        }
    }
    __syncthreads();
    int cnt = min(mcnt, CAP);

    // ---- 2) stable rank sort by (tz, original idx) ----
    for (int j = tid; j < cnt; j += 512) {
        float kj = Mkey[j];
        int   ij = Midx[j];
        int r = 0;
        for (int k = 0; k < cnt; ++k) {
            float kk = Mkey[k];
            r += (kk < kj || (kk == kj && Midx[k] < ij)) ? 1 : 0;
        }
        Msrt[r] = j;
    }
    __syncthreads();

    // ---- 3) composite: wave wv takes sorted chunk wv ----
    int px_i = tx * TS + (lane & 7);
    int py_i = ty * TS + (lane >> 3);
    float gx = (float)px_i, gy = (float)py_i;

    int L = (cnt + NW - 1) / NW;
    int start = wv * L;
    int end   = min(start + L, cnt);

    float T = 1.0f, C0 = 0.0f, C1 = 0.0f, C2 = 0.0f, D = 0.0f;
    for (int g2 = start; g2 < end; ++g2) {
        int s = Msrt[g2];
        float4 f0 = *(const float4*)&Mrec[s][0];   // px, py, h0, h1
        float4 f1 = *(const float4*)&Mrec[s][4];   // h2, l2op, cr, cg
        float4 f2 = *(const float4*)&Mrec[s][8];   // cb, tz, -, -
        float dx = f0.x - gx, dy = f0.y - gy;
        float p2 = f0.z*dx*dx + f0.w*dx*dy + f1.x*dy*dy;   // power*log2e
        float al = fminf(0.99f, exp2f(p2 + f1.y));
        bool keep = (p2 <= 0.0f) && (al >= A_MIN);
        float a = keep ? al : 0.0f;
        float w = T * a;
        C0 = fmaf(w, f1.z, C0);
        C1 = fmaf(w, f1.w, C1);
        C2 = fmaf(w, f2.x, C2);
        D  = fmaf(w, f2.y, D);
        T -= w;                                    // T *= (1-a)
    }

    Lpart[wv][0][lane] = T;
    Lpart[wv][1][lane] = C0;
    Lpart[wv][2][lane] = C1;
    Lpart[wv][3][lane] = C2;
    Lpart[wv][4][lane] = D;
    __syncthreads();

    if (wv == 0) {
        float Tt = 1.0f, c0 = 0.0f, c1 = 0.0f, c2 = 0.0f, d = 0.0f;
        #pragma unroll
        for (int s = 0; s < NW; ++s) {
            c0 = fmaf(Tt, Lpart[s][1][lane], c0);
            c1 = fmaf(Tt, Lpart[s][2][lane], c1);
            c2 = fmaf(Tt, Lpart[s][3][lane], c2);
            d  = fmaf(Tt, Lpart[s][4][lane], d);
            Tt *= Lpart[s][0][lane];
        }
        int pix = py_i * IMG_W + px_i;
        out[O_COLOR + 0*HW + pix] = c0 + bg[0] * Tt;
        out[O_COLOR + 1*HW + pix] = c1 + bg[1] * Tt;
        out[O_COLOR + 2*HW + pix] = c2 + bg[2] * Tt;
        out[O_DEPTH + pix] = d;
        out[O_OPAC  + pix] = 1.0f - Tt;
    }

    // ---- 4) radii + n_touched: blocks 0..255, one gaussian per wave ----
    if (tile < NG / NW) {
        int gi = tile * NW + wv;
        G g = g_chain(gi, means3D, opac, cols, scales, rots, vm);
        if (!g.valid) {
            if (lane == 0) { out[O_RADII + gi] = 0.0f; out[O_NT + gi] = 0.0f; }
        } else {
            int x0 = max(0, (int)ceilf(g.px - g.dxm));
            int x1 = min(IMG_W - 1, (int)floorf(g.px + g.dxm));
            int y0 = max(0, (int)ceilf(g.py - g.dym));
            int y1 = min(IMG_H - 1, (int)floorf(g.py + g.dym));
            int cntp = 0;
            for (int yy = y0; yy <= y1; ++yy) {
                float dy = g.py - (float)yy;
                for (int xb = x0; xb <= x1; xb += 64) {
                    int xx = xb + lane;
                    float dx = g.px - (float)xx;
                    float p2 = g.h0*dx*dx + g.h1*dx*dy + g.h2*dy*dy;
                    bool keep = (xx <= x1) && (p2 <= 0.0f)
                             && (exp2f(p2 + g.l2op) >= A_MIN);
                    cntp += (int)__popcll(__ballot(keep));
                }
            }
            if (lane == 0) {
                out[O_RADII + gi] = g.radf;
                out[O_NT + gi] = (float)cntp;
            }
        }
    }
}

extern "C" void kernel_launch(void* const* d_in, const int* in_sizes, int n_in,
                              void* d_out, int out_size, void* d_ws, size_t ws_size,
                              hipStream_t stream)
{
    const float* means3D = (const float*)d_in[0];
    // d_in[1] = means2D (unused)
    const float* opac    = (const float*)d_in[2];
    const float* cols    = (const float*)d_in[3];
    const float* scales  = (const float*)d_in[4];
    const float* rots    = (const float*)d_in[5];
    const float* bg      = (const float*)d_in[6];
    const float* vm      = (const float*)d_in[7];
    float* out = (float*)d_out;

    hipLaunchKernelGGL(k_mega, dim3(NTILE), dim3(512), 0, stream,
                       means3D, opac, cols, scales, rots, vm, bg, out);
}

// Round 13
// 15.881 us; speedup vs baseline: 1.5315x; 1.5315x over previous
//
#include <hip/hip_runtime.h>
#include <math.h>

namespace {

constexpr int NG     = 2048;
constexpr int IMG_H  = 160;
constexpr int IMG_W  = 224;
constexpr int HW     = IMG_H * IMG_W;   // 35840
constexpr int TS     = 8;               // tile size (8x8 px)
constexpr int TX     = IMG_W / TS;      // 28
constexpr int TYN    = IMG_H / TS;      // 20
constexpr int NTILE  = TX * TYN;        // 560

constexpr int NSEG   = 8;               // depth segments (one wave each)
constexpr int SEGS   = NG / NSEG;       // 256 slots per segment

constexpr int PRB    = 256;             // k_prerank blocks
constexpr int OWN    = NG / PRB;        // 8 own gaussians per block (1 per wave)

constexpr float TFX   = 0.5774f;
constexpr float TFY   = (float)(0.5774 * 160.0 / 224.0);
constexpr float ITFX  = (float)(1.0 / 0.5774);
constexpr float ITFY  = (float)(1.0 / (0.5774 * 160.0 / 224.0));
constexpr float FXC   = (float)(224.0 / (2.0 * 0.5774));
constexpr float FYC   = (float)(160.0 / (2.0 * (0.5774 * 160.0 / 224.0)));
constexpr float LIMX  = (float)(1.3 * 0.5774);
constexpr float LIMY  = (float)(1.3 * (0.5774 * 160.0 / 224.0));
constexpr float A_MIN = (float)(1.0 / 255.0);
constexpr float NEARP = 0.2f;
constexpr float LOWPASS = 0.3f;
constexpr float L2E   = 1.4426950408889634f;   // log2(e)
constexpr float LN2   = 0.6931471805599453f;
constexpr float L2_255 = 7.994353436858858f;   // log2(255)

// output float offsets (flat, in return order)
constexpr int O_COLOR = 0;
constexpr int O_RADII = 3 * HW;           // 107520
constexpr int O_DEPTH = O_RADII + NG;     // 109568
constexpr int O_OPAC  = O_DEPTH + HW;     // 145408
constexpr int O_NT    = O_OPAC + HW;      // 181248

// workspace offsets (4B units)
// AoS record (12 floats): [0]px [1]py [2]dxm [3]dym | [4]h0 [5]h1 [6]h2 [7]l2op | [8]r [9]g [10]b [11]dep
constexpr int W_S    = 0;          // sorted AoS, NG*12 floats
constexpr int W_ORG  = 12 * NG;    // int: original index per sorted slot
constexpr int W_PB   = 13 * NG;    // sorted packed tile bbox, NG uints

// inbuf layout (112 floats): [0..23] means3D, [24..55] rots, [56..79] scales,
// [80..103] cols, [104..111] opac — for the block's 8 own gaussians
constexpr int IB_M = 0, IB_Q = 24, IB_S = 56, IB_C = 80, IB_O = 104;

} // namespace

// Fused preprocess + stable rank sort (R10 structure, micro-tuned):
//  - 512 threads: phase A = 4 cheap keys/thread; phase B = 1 rank/wave.
//  - own-gaussian inputs staged to LDS at kernel entry (latency hidden
//    under phases A+B); phase C reads LDS.
//  - phase C uses fast rcp/rsq/log2 (rel err ~1e-7, validated R12).
__global__ __launch_bounds__(512) void k_prerank(const float* __restrict__ means3D,
                                                 const float* __restrict__ opac,
                                                 const float* __restrict__ cols,
                                                 const float* __restrict__ scales,
                                                 const float* __restrict__ rots,
                                                 const float* __restrict__ vm,
                                                 float* __restrict__ wsf,
                                                 int* __restrict__ wsi,
                                                 unsigned* __restrict__ wsu,
                                                 float* __restrict__ out)
{
    __shared__ float sk[NG];
    __shared__ int   rbuf[OWN];
    __shared__ float inbuf[112];

    int tid = threadIdx.x;
    int b   = blockIdx.x;
    int i0  = b * OWN;

    // ---- issue-early: stage own gaussians' inputs (consumed in phase C) ----
    if (tid < 112) {
        float v;
        if      (tid < 24)  v = means3D[3*i0 + tid];
        else if (tid < 56)  v = rots[4*i0 + (tid - 24)];
        else if (tid < 80)  v = scales[3*i0 + (tid - 56)];
        else if (tid < 104) v = cols[3*i0 + (tid - 80)];
        else                v = opac[i0 + (tid - 104)];
        inbuf[tid] = v;
    }

    // ---- phase A: cheap keys for all NG (4 per thread, 3 FMAs each) ----
    float R20k = vm[8], R21k = vm[9], R22k = vm[10], T2k = vm[11];
    #pragma unroll
    for (int j = 0; j < NG / 512; ++j) {
        int g = tid + 512 * j;
        float tzk = R20k*means3D[3*g] + R21k*means3D[3*g+1] + R22k*means3D[3*g+2] + T2k;
        sk[g] = (tzk > NEARP) ? tzk : INFINITY;
    }
    __syncthreads();

    // ---- phase B: wave w ranks own gaussian i0+w (stable: (key, idx)) ----
    int w = tid >> 6, lane = tid & 63;
    {
        int i = i0 + w;
        float ki = sk[i];
        int r = 0;
        #pragma unroll
        for (int u = 0; u < NG / 64; ++u) {      // stride-64: 2 lanes/bank, free
            int j = lane + 64 * u;
            float kk = sk[j];
            r += (kk < ki || (kk == ki && j < i)) ? 1 : 0;
        }
        r += __shfl_xor(r, 1);
        r += __shfl_xor(r, 2);
        r += __shfl_xor(r, 4);
        r += __shfl_xor(r, 8);
        r += __shfl_xor(r, 16);
        r += __shfl_xor(r, 32);
        if (lane == 0) rbuf[w] = r;
    }
    __syncthreads();

    // ---- phase C: full chain once per own gaussian, scatter sorted ----
    if (tid < OWN) {
        int i = i0 + tid;
        int r = rbuf[tid];

        float R00 = vm[0], R01 = vm[1], R02 = vm[2],  T0 = vm[3];
        float R10 = vm[4], R11 = vm[5], R12 = vm[6],  T1 = vm[7];
        float R20 = vm[8], R21 = vm[9], R22 = vm[10], T2 = vm[11];

        float mx = inbuf[IB_M + 3*tid], my = inbuf[IB_M + 3*tid+1], mz = inbuf[IB_M + 3*tid+2];
        float tx = R00*mx + R01*my + R02*mz + T0;
        float ty = R10*mx + R11*my + R12*mz + T1;
        float tz = R20*mx + R21*my + R22*mz + T2;

        float itz = __builtin_amdgcn_rcpf(tz);
        float xr  = tx * itz, yr = ty * itz;
        float txz = fminf(LIMX, fmaxf(-LIMX, xr)) * tz;
        float tyz = fminf(LIMY, fmaxf(-LIMY, yr)) * tz;

        float qw = inbuf[IB_Q + 4*tid], qx = inbuf[IB_Q + 4*tid+1];
        float qy = inbuf[IB_Q + 4*tid+2], qz = inbuf[IB_Q + 4*tid+3];
        float qn = __builtin_amdgcn_rsqf(qw*qw + qx*qx + qy*qy + qz*qz);
        qw *= qn; qx *= qn; qy *= qn; qz *= qn;
        float r00 = 1.0f - 2.0f*(qy*qy + qz*qz), r01 = 2.0f*(qx*qy - qw*qz), r02 = 2.0f*(qx*qz + qw*qy);
        float r10 = 2.0f*(qx*qy + qw*qz), r11 = 1.0f - 2.0f*(qx*qx + qz*qz), r12 = 2.0f*(qy*qz - qw*qx);
        float r20 = 2.0f*(qx*qz - qw*qy), r21 = 2.0f*(qy*qz + qw*qx), r22 = 1.0f - 2.0f*(qx*qx + qy*qy);

        float s0 = inbuf[IB_S + 3*tid];   s0 = s0 * s0;
        float s1 = inbuf[IB_S + 3*tid+1]; s1 = s1 * s1;
        float s2 = inbuf[IB_S + 3*tid+2]; s2 = s2 * s2;

        float S00 = r00*r00*s0 + r01*r01*s1 + r02*r02*s2;
        float S01 = r00*r10*s0 + r01*r11*s1 + r02*r12*s2;
        float S02 = r00*r20*s0 + r01*r21*s1 + r02*r22*s2;
        float S11 = r10*r10*s0 + r11*r11*s1 + r12*r12*s2;
        float S12 = r10*r20*s0 + r11*r21*s1 + r12*r22*s2;
        float S22 = r20*r20*s0 + r21*r21*s1 + r22*r22*s2;

        float j00 = FXC * itz;
        float j02 = -FXC * txz * itz * itz;
        float j11 = FYC * itz;
        float j12 = -FYC * tyz * itz * itz;

        float Tm00 = j00*R00 + j02*R20, Tm01 = j00*R01 + j02*R21, Tm02 = j00*R02 + j02*R22;
        float Tm10 = j11*R10 + j12*R20, Tm11 = j11*R11 + j12*R21, Tm12 = j11*R12 + j12*R22;

        float M00 = Tm00*S00 + Tm01*S01 + Tm02*S02;
        float M01 = Tm00*S01 + Tm01*S11 + Tm02*S12;
        float M02 = Tm00*S02 + Tm01*S12 + Tm02*S22;
        float M10 = Tm10*S00 + Tm11*S01 + Tm12*S02;
        float M11 = Tm10*S01 + Tm11*S11 + Tm12*S12;
        float M12 = Tm10*S02 + Tm11*S12 + Tm12*S22;

        float cov00 = M00*Tm00 + M01*Tm01 + M02*Tm02;
        float cov01 = M00*Tm10 + M01*Tm11 + M02*Tm12;
        float cov11 = M10*Tm10 + M11*Tm11 + M12*Tm12;

        float a = cov00 + LOWPASS;
        float bb = cov01;
        float c = cov11 + LOWPASS;
        float det = a*c - bb*bb;
        float dinv = __builtin_amdgcn_rcpf(det);
        float con0 = c * dinv, con1 = -bb * dinv, con2 = a * dinv;

        float mid  = 0.5f * (a + c);
        float lam1 = mid + sqrtf(fmaxf(0.1f, mid*mid - det));
        float radf = ceilf(3.0f * sqrtf(lam1));

        float px = ((xr * ITFX + 1.0f) * (float)IMG_W - 1.0f) * 0.5f;
        float py = ((yr * ITFY + 1.0f) * (float)IMG_H - 1.0f) * 0.5f;

        bool valid = (tz > NEARP) && (det > 0.0f) && (radf > 0.0f);

        float op   = inbuf[IB_O + tid];
        float l2op = __log2f(op);
        float tlin = fmaxf(0.0f, (l2op + L2_255) * LN2);
        float dxm  = sqrtf(2.0f * tlin * a) * 1.001f + 0.1f;
        float dym  = sqrtf(2.0f * tlin * c) * 1.001f + 0.1f;

        int itx0 = (int)floorf((px - dxm) * (1.0f / TS));
        int itx1 = (int)floorf((px + dxm) * (1.0f / TS));
        int ity0 = (int)floorf((py - dym) * (1.0f / TS));
        int ity1 = (int)floorf((py + dym) * (1.0f / TS));
        unsigned pb;
        if (!valid || itx1 < 0 || ity1 < 0 || itx0 >= TX || ity0 >= TYN) {
            pb = 0xFFFFFFFFu;   // empty: tx0=255 never <= tx
        } else {
            unsigned a0 = (unsigned)max(itx0, 0);
            unsigned a1 = (unsigned)max(ity0, 0);
            unsigned a2 = (unsigned)min(itx1, TX - 1);
            unsigned a3 = (unsigned)min(ity1, TYN - 1);
            pb = a0 | (a1 << 8) | (a2 << 16) | (a3 << 24);
        }

        float4 f0, f1, f2;
        if (valid) {
            f0 = make_float4(px, py, dxm, dym);
            f1 = make_float4(-0.5f*con0*L2E, -con1*L2E, -0.5f*con2*L2E, l2op);
            f2 = make_float4(inbuf[IB_C + 3*tid], inbuf[IB_C + 3*tid+1], inbuf[IB_C + 3*tid+2], tz);
        } else {
            f0 = make_float4(1e9f, 1e9f, -1.0f, -1.0f);
            f1 = make_float4(0.0f, 0.0f, 0.0f, -1000.0f);
            f2 = make_float4(0.0f, 0.0f, 0.0f, 0.0f);
        }
        float4* dst = (float4*)&wsf[W_S + r*12];
        dst[0] = f0; dst[1] = f1; dst[2] = f2;
        wsu[W_PB + r]  = pb;
        wsi[W_ORG + r] = i;
        out[O_RADII + i] = valid ? radf : 0.0f;
        out[O_NT + i] = 0.0f;                    // re-zeroed every call
    }
}

// One block per tile; wave wv composites depth-segment wv; in-block combine.
__global__ __launch_bounds__(512) void k_rast(const float* __restrict__ wsf,
                                              const int* __restrict__ wsi,
                                              const unsigned* __restrict__ wsu,
                                              const float* __restrict__ bg,
                                              float* __restrict__ out)
{
    __shared__ int   Llist[NSEG][SEGS];   // 8 KB
    __shared__ int   Lcnt[NSEG][SEGS];    // 8 KB
    __shared__ float Ls[NSEG][64][12];    // 24 KB
    __shared__ float Lpart[NSEG][5][64];  // 10 KB

    int tid  = threadIdx.x;
    int lane = tid & 63;
    int wv   = tid >> 6;
    int tile = blockIdx.x;
    int tx = tile % TX, ty = tile / TX;
    int base0 = wv * SEGS;

    // ---- scan this segment's packed tile ranges (ballot-compact, order kept) ----
    int cnt = 0;
    #pragma unroll
    for (int c = 0; c < SEGS / 64; ++c) {
        unsigned w = wsu[W_PB + base0 + c * 64 + lane];
        bool keep = ((w & 255u) <= (unsigned)tx) && ((unsigned)tx <= ((w >> 16) & 255u))
                 && (((w >> 8) & 255u) <= (unsigned)ty) && ((unsigned)ty <= (w >> 24));
        unsigned long long m = __ballot(keep);
        if (keep) Llist[wv][cnt + __popcll(m & ((1ull << lane) - 1ull))] = base0 + c * 64 + lane;
        cnt += (int)__popcll(m);
    }

    // ---- composite: each lane owns one pixel of the 8x8 tile ----
    int px_i = tx * TS + (lane & 7);
    int py_i = ty * TS + (lane >> 3);
    float gx = (float)px_i, gy = (float)py_i;

    float T = 1.0f, C0 = 0.0f, C1 = 0.0f, C2 = 0.0f, D = 0.0f;

    for (int b2 = 0; b2 < cnt; b2 += 64) {
        int cl = min(64, cnt - b2);
        if (lane < cl) {
            int e = Llist[wv][b2 + lane];
            const float4* s4 = (const float4*)&wsf[W_S + e*12];
            *(float4*)&Ls[wv][lane][0] = s4[0];
            *(float4*)&Ls[wv][lane][4] = s4[1];
            *(float4*)&Ls[wv][lane][8] = s4[2];
        }
        #pragma unroll 2
        for (int g = 0; g < cl; ++g) {
            float4 f0 = *(const float4*)&Ls[wv][g][0];   // px, py, (dxm, dym)
            float4 f1 = *(const float4*)&Ls[wv][g][4];   // h0, h1, h2, l2op
            float4 f2 = *(const float4*)&Ls[wv][g][8];   // r, g, b, dep
            float dx = f0.x - gx, dy = f0.y - gy;
            float p2 = f1.x*dx*dx + f1.y*dx*dy + f1.z*dy*dy;   // power*log2e
            float al = fminf(0.99f, exp2f(p2 + f1.w));
            bool keep = (p2 <= 0.0f) && (al >= A_MIN);
            float a = keep ? al : 0.0f;
            float w = T * a;
            C0 = fmaf(w, f2.x, C0);
            C1 = fmaf(w, f2.y, C1);
            C2 = fmaf(w, f2.z, C2);
            D  = fmaf(w, f2.w, D);
            T -= w;                                   // T *= (1-a)
            unsigned long long m = __ballot(keep);
            if (lane == g) Lcnt[wv][b2 + g] = (int)__popcll(m);
        }
    }

    Lpart[wv][0][lane] = T;
    Lpart[wv][1][lane] = C0;
    Lpart[wv][2][lane] = C1;
    Lpart[wv][3][lane] = C2;
    Lpart[wv][4][lane] = D;

    // ---- batched n_touched flush (order-independent exact float atomics) ----
    for (int j = lane; j < cnt; j += 64) {
        int c = Lcnt[wv][j];
        if (c > 0) atomicAdd(out + O_NT + wsi[W_ORG + Llist[wv][j]], (float)c);
    }

    __syncthreads();

    // ---- in-block combine (wave 0), depth order over segments ----
    if (wv == 0) {
        float Tt = 1.0f, c0 = 0.0f, c1 = 0.0f, c2 = 0.0f, d = 0.0f;
        #pragma unroll
        for (int s = 0; s < NSEG; ++s) {
            c0 = fmaf(Tt, Lpart[s][1][lane], c0);
            c1 = fmaf(Tt, Lpart[s][2][lane], c1);
            c2 = fmaf(Tt, Lpart[s][3][lane], c2);
            d  = fmaf(Tt, Lpart[s][4][lane], d);
            Tt *= Lpart[s][0][lane];
        }
        int pix = py_i * IMG_W + px_i;
        out[O_COLOR + 0*HW + pix] = c0 + bg[0] * Tt;
        out[O_COLOR + 1*HW + pix] = c1 + bg[1] * Tt;
        out[O_COLOR + 2*HW + pix] = c2 + bg[2] * Tt;
        out[O_DEPTH + pix] = d;
        out[O_OPAC  + pix] = 1.0f - Tt;
    }
}

extern "C" void kernel_launch(void* const* d_in, const int* in_sizes, int n_in,
                              void* d_out, int out_size, void* d_ws, size_t ws_size,
                              hipStream_t stream)
{
    const float* means3D = (const float*)d_in[0];
    // d_in[1] = means2D (unused)
    const float* opac    = (const float*)d_in[2];
    const float* cols    = (const float*)d_in[3];
    const float* scales  = (const float*)d_in[4];
    const float* rots    = (const float*)d_in[5];
    const float* bg      = (const float*)d_in[6];
    const float* vm      = (const float*)d_in[7];
    float* out = (float*)d_out;
    float* wsf = (float*)d_ws;
    int*   wsi = (int*)d_ws;
    unsigned* wsu = (unsigned*)d_ws;

    hipLaunchKernelGGL(k_prerank, dim3(PRB), dim3(512), 0, stream,
                       means3D, opac, cols, scales, rots, vm, wsf, wsi, wsu, out);
    hipLaunchKernelGGL(k_rast, dim3(NTILE), dim3(512), 0, stream,
                       wsf, wsi, wsu, bg, out);
}